// Round 8
// baseline (24.306 us; speedup 1.0000x reference)
//
#include <hip/hip_runtime.h>
#include <math.h>

#define NQ    12
#define TPB   256
#define DEPTH 4

typedef float v2f __attribute__((ext_vector_type(2)));

__device__ __forceinline__ v2f splat(float s) { return (v2f){s, s}; }

// Forced VOP3P packed math (hypothesis: clang scalarizes elementwise ops)
__device__ __forceinline__ v2f pk_mul(v2f a, v2f b) {
    v2f d;
    asm("v_pk_mul_f32 %0, %1, %2" : "=v"(d) : "v"(a), "v"(b));
    return d;
}
__device__ __forceinline__ v2f pk_fma(v2f a, v2f b, v2f c) {
    v2f d;
    asm("v_pk_fma_f32 %0, %1, %2, %3" : "=v"(d) : "v"(a), "v"(b), "v"(c));
    return d;
}

// readlane broadcast of a float (literal lane index), pure VALU/SALU
#define RL(v, l) __uint_as_float(__builtin_amdgcn_readlane(__float_as_uint(v), (l)))

// ---- cross-lane helpers (VALU pipe) ------------------------------------
template<int CTRL>
__device__ __forceinline__ float dppf(float v) {
    int r = __builtin_amdgcn_update_dpp(0, __float_as_int(v), CTRL, 0xF, 0xF, true);
    return __int_as_float(r);
}
template<int CTRL>
__device__ __forceinline__ v2f dpp2(v2f v) {
    v2f r;
    r.x = dppf<CTRL>(v.x);
    r.y = dppf<CTRL>(v.y);
    return r;
}

#if __has_builtin(__builtin_amdgcn_permlane32_swap)
#define HAVE_PL32 1
#else
#define HAVE_PL32 0
#endif
#if __has_builtin(__builtin_amdgcn_permlane16_swap)
#define HAVE_PL16 1
#else
#define HAVE_PL16 0
#endif

__device__ __forceinline__ void split32v(v2f v, v2f& v0, v2f& v1) {
#if HAVE_PL32
    auto rx = __builtin_amdgcn_permlane32_swap(__float_as_uint(v.x), __float_as_uint(v.x), false, false);
    auto ry = __builtin_amdgcn_permlane32_swap(__float_as_uint(v.y), __float_as_uint(v.y), false, false);
    v0 = (v2f){__uint_as_float(rx[0]), __uint_as_float(ry[0])};
    v1 = (v2f){__uint_as_float(rx[1]), __uint_as_float(ry[1])};
#else
    v2f p;
    p.x = __shfl_xor(v.x, 32, 64);
    p.y = __shfl_xor(v.y, 32, 64);
    int bit = (__lane_id() >> 5) & 1;
    v0 = bit ? p : v;
    v1 = bit ? v : p;
#endif
}
__device__ __forceinline__ void split16v(v2f v, v2f& v0, v2f& v1) {
#if HAVE_PL16
    auto rx = __builtin_amdgcn_permlane16_swap(__float_as_uint(v.x), __float_as_uint(v.x), false, false);
    auto ry = __builtin_amdgcn_permlane16_swap(__float_as_uint(v.y), __float_as_uint(v.y), false, false);
    v0 = (v2f){__uint_as_float(rx[0]), __uint_as_float(ry[0])};
    v1 = (v2f){__uint_as_float(rx[1]), __uint_as_float(ry[1])};
#else
    v2f p;
    p.x = __shfl_xor(v.x, 16, 64);
    p.y = __shfl_xor(v.y, 16, 64);
    int bit = (__lane_id() >> 4) & 1;
    v0 = bit ? p : v;
    v1 = bit ? v : p;
#endif
}
__device__ __forceinline__ void split16(float v, float& v0, float& v1) {
#if HAVE_PL16
    auto r = __builtin_amdgcn_permlane16_swap(__float_as_uint(v), __float_as_uint(v), false, false);
    v0 = __uint_as_float(r[0]);
    v1 = __uint_as_float(r[1]);
#else
    float p = __shfl_xor(v, 16, 64);
    int bit = (__lane_id() >> 4) & 1;
    v0 = bit ? p : v;
    v1 = bit ? v : p;
#endif
}
__device__ __forceinline__ void split32(float v, float& v0, float& v1) {
#if HAVE_PL32
    auto r = __builtin_amdgcn_permlane32_swap(__float_as_uint(v), __float_as_uint(v), false, false);
    v0 = __uint_as_float(r[0]);
    v1 = __uint_as_float(r[1]);
#else
    float p = __shfl_xor(v, 32, 64);
    int bit = (__lane_id() >> 5) & 1;
    v0 = bit ? p : v;
    v1 = bit ? v : p;
#endif
}

// ---- butterfly variants (state: a[e] = (re, im) packed) ----------------
template<int ST>
__device__ __forceinline__ void reg_wire(v2f a[16], float cy, float sy) {
    const v2f cc = splat(cy), ss = splat(sy), ns = splat(-sy);
    #pragma unroll
    for (int e0 = 0; e0 < 16; ++e0) {
        if ((e0 & ST) == 0) {
            const int e1 = e0 | ST;
            v2f A0 = a[e0], A1 = a[e1];
            a[e0] = pk_fma(ns, A1, pk_mul(cc, A0));
            a[e1] = pk_fma(ss, A0, pk_mul(cc, A1));
        }
    }
}

template<int CTRL>
__device__ __forceinline__ void dpp_wire(v2f a[16], float cy, float sy, int bit) {
    const v2f cc = splat(cy), sv = splat(bit ? sy : -sy);
    #pragma unroll
    for (int e = 0; e < 16; ++e) {
        v2f p = dpp2<CTRL>(a[e]);
        a[e] = pk_fma(sv, p, pk_mul(cc, a[e]));
    }
}

// mask 4: row_shr:4 sources lane i-4 (bit==1), row_shl:4 sources i+4 (bit==0)
__device__ __forceinline__ void xor4_wire(v2f a[16], float cy, float sy, int bit) {
    const v2f cc = splat(cy), sv = splat(bit ? sy : -sy);
    #pragma unroll
    for (int e = 0; e < 16; ++e) {
        v2f pS = dpp2<0x114>(a[e]);
        v2f pL = dpp2<0x104>(a[e]);
        v2f p = bit ? pS : pL;
        a[e] = pk_fma(sv, p, pk_mul(cc, a[e]));
    }
}

template<bool IS32>
__device__ __forceinline__ void pl_wire(v2f a[16], float cy, float sy, int bit) {
    const v2f ka = splat(bit ? sy : cy), kb = splat(bit ? cy : -sy);
    #pragma unroll
    for (int e = 0; e < 16; ++e) {
        v2f A0, A1;
        if constexpr (IS32) split32v(a[e], A0, A1);
        else                split16v(a[e], A0, A1);
        a[e] = pk_fma(ka, A0, pk_mul(kb, A1));
    }
}

__device__ __forceinline__ float wave_sum(float y) {
    y += dppf<0xB1>(y);
    y += dppf<0x4E>(y);
    y += dppf<0x124>(y);    // row_ror:4
    y += dppf<0x128>(y);    // row_ror:8
    float a, b;
    split16(y, a, b); y = a + b;
    split32(y, a, b); y = a + b;
    return y;
}

__global__ __launch_bounds__(TPB) void qsim_kernel(
    const float* __restrict__ x,        // (512, 12)
    const float* __restrict__ params,   // (48, 12)
    const float* __restrict__ head_w,   // (2, 12)
    const float* __restrict__ head_b,   // (2,)
    float* __restrict__ out)            // (512, 2)
{
    __shared__ float4 exch[2][8][TPB];  // 64 KB double-buffered exchange
    __shared__ float  red[4][13];

    const int b = blockIdx.x;
    const int t = threadIdx.x;
    const int l = t & 63;

    // One sincos per lane:
    //   lanes 0..47  -> RY angle (d,i): 0.5*params[l*12 + l%12]
    //   lanes 48..59 -> RX angle 0.5*x[b*12 + (l-48)]
    float cv, sv;
    {
        int li   = l % 12;
        int idx1 = (l < 48) ? (l * 12 + li) : 0;
        float v1 = params[idx1];
        int i2   = l - 48;
        int idx2 = (i2 >= 0 && i2 < 12) ? (b * 12 + i2) : 0;
        float v2 = x[idx2];
        float th = 0.5f * ((l < 48) ? v1 : ((i2 >= 0 && i2 < 12) ? v2 : 0.0f));
        __sincosf(th, &sv, &cv);
    }
    #define CY(d, w) RL(cv, (d) * 12 + (w))
    #define SY(d, w) RL(sv, (d) * 12 + (w))

    // state: amp index k = (t<<4)|e ; a[e] = (re, im)
    v2f a[16];
    {
        float cx[12], sx[12];
        #pragma unroll
        for (int i = 0; i < 12; ++i) {
            cx[i] = RL(cv, 48 + i);
            sx[i] = RL(sv, 48 + i);
        }
        float P = 1.0f;
        #pragma unroll
        for (int j = 0; j < 8; ++j)
            P *= ((t >> (7 - j)) & 1) ? sx[j] : cx[j];
        float qh[4], ql[4];
        qh[0] = cx[8] * cx[9];  qh[1] = cx[8] * sx[9];
        qh[2] = sx[8] * cx[9];  qh[3] = sx[8] * sx[9];
        ql[0] = cx[10] * cx[11]; ql[1] = cx[10] * sx[11];
        ql[2] = sx[10] * cx[11]; ql[3] = sx[10] * sx[11];
        int p = __popc(t) & 3;
        float ur = (p == 0) ? 1.f : ((p == 2) ? -1.f : 0.f);
        float ui = (p == 1) ? -1.f : ((p == 3) ? 1.f : 0.f);
        v2f u[4] = { (v2f){ur, ui}, (v2f){ui, -ur}, (v2f){-ur, -ui}, (v2f){-ui, ur} };
        #pragma unroll
        for (int e = 0; e < 16; ++e) {
            float m = P * qh[e >> 2] * ql[e & 3];
            a[e] = splat(m) * u[__popc(e) & 3];
        }
    }

    // CZ signs as v2f +-1 (negate where popc(k & (k>>1)) odd)
    v2f czv[16];
    #pragma unroll
    for (int e = 0; e < 16; ++e) {
        int k = (t << 4) | e;
        float sgn = __int_as_float(0x3f800000u | (unsigned)((__popc(k & (k >> 1)) & 1) << 31));
        czv[e] = splat(sgn);
    }

    const int wa = (t >> 7) & 1;   // wire-0 bit
    const int wb = (t >> 6) & 1;   // wire-1 bit
    const int tb = t ^ 64, ta = t ^ 128, tab = t ^ 192;

    #pragma unroll
    for (int d = 0; d < DEPTH; ++d) {
        // elem-bit wires 8..11
        reg_wire<8>(a, CY(d, 8),  SY(d, 8));
        reg_wire<4>(a, CY(d, 9),  SY(d, 9));
        reg_wire<2>(a, CY(d, 10), SY(d, 10));
        reg_wire<1>(a, CY(d, 11), SY(d, 11));

        // lane-bit wires 2..7 (all VALU pipe)
        pl_wire<true >(a, CY(d, 2), SY(d, 2), (t >> 5) & 1);
        pl_wire<false>(a, CY(d, 3), SY(d, 3), (t >> 4) & 1);
        dpp_wire<0x128>(a, CY(d, 4), SY(d, 4), (t >> 3) & 1); // xor 8
        xor4_wire      (a, CY(d, 5), SY(d, 5), (t >> 2) & 1); // xor 4
        dpp_wire<0x4E >(a, CY(d, 6), SY(d, 6), (t >> 1) & 1); // xor 2
        dpp_wire<0xB1 >(a, CY(d, 7), SY(d, 7), (t     ) & 1); // xor 1

        // wires 0,1 fused: 4-way exchange across thread bits 7,6 via LDS.
        // Double-buffered, one barrier per depth (R5 hazard argument).
        {
            const float c0 = CY(d, 0), s0 = SY(d, 0);
            const float c1 = CY(d, 1), s1 = SY(d, 1);
            const float sa = wa ? s0 : -s0;
            const float sb = wb ? s1 : -s1;
            const v2f koo = splat(c0 * c1);
            const v2f kb2 = splat(c0 * sb);   // partner t^64
            const v2f ka2 = splat(sa * c1);   // partner t^128
            const v2f kab = splat(sa * sb);   // partner t^192

            float4 (*buf)[TPB] = exch[d & 1];
            #pragma unroll
            for (int j = 0; j < 4; ++j)
                buf[j][t]     = make_float4(a[2*j].x,   a[2*j].y,   a[2*j+1].x,   a[2*j+1].y);
            #pragma unroll
            for (int j = 0; j < 4; ++j)
                buf[4 + j][t] = make_float4(a[8+2*j].x, a[8+2*j].y, a[8+2*j+1].x, a[8+2*j+1].y);
            __syncthreads();
            #pragma unroll
            for (int j = 0; j < 8; ++j) {
                float4 B  = buf[j][tb];
                float4 A  = buf[j][ta];
                float4 AB = buf[j][tab];
                v2f r0 = pk_mul(koo, a[2*j]);
                v2f r1 = pk_mul(koo, a[2*j+1]);
                r0 = pk_fma(kb2, (v2f){B.x,  B.y},  r0);
                r1 = pk_fma(kb2, (v2f){B.z,  B.w},  r1);
                r0 = pk_fma(ka2, (v2f){A.x,  A.y},  r0);
                r1 = pk_fma(ka2, (v2f){A.z,  A.w},  r1);
                a[2*j]   = pk_fma(kab, (v2f){AB.x, AB.y}, r0);
                a[2*j+1] = pk_fma(kab, (v2f){AB.z, AB.w}, r1);
            }
        }

        // CZ signs (skip last depth: |amp|^2 unaffected)
        if (d < DEPTH - 1) {
            #pragma unroll
            for (int e = 0; e < 16; ++e)
                a[e] = pk_mul(a[e], czv[e]);
        }
    }

    // ---- reduction: T and per-wire S ----
    v2f t2 = splat(0.f), q0 = splat(0.f), q1 = splat(0.f), q2 = splat(0.f), q3 = splat(0.f);
    #pragma unroll
    for (int e = 0; e < 16; ++e) {
        v2f ae = a[e];
        t2 = pk_fma(ae, ae, t2);
        if (e & 8) q0 = pk_fma(ae, ae, q0);
        if (e & 4) q1 = pk_fma(ae, ae, q1);
        if (e & 2) q2 = pk_fma(ae, ae, q2);
        if (e & 1) q3 = pk_fma(ae, ae, q3);
    }
    float T = t2.x + t2.y;
    float v[13];
    v[0] = T;
    #pragma unroll
    for (int w = 0; w < 8; ++w)
        v[1 + w] = ((t >> (7 - w)) & 1) ? T : 0.0f;   // wires 0..7
    v[9]  = q0.x + q0.y;
    v[10] = q1.x + q1.y;
    v[11] = q2.x + q2.y;
    v[12] = q3.x + q3.y;

    #pragma unroll
    for (int i = 0; i < 13; ++i)
        v[i] = wave_sum(v[i]);

    if ((t & 63) == 0) {
        #pragma unroll
        for (int i = 0; i < 13; ++i) red[t >> 6][i] = v[i];
    }
    __syncthreads();

    if (t == 0) {
        float Tt = red[0][0] + red[1][0] + red[2][0] + red[3][0];
        float l0 = head_b[0], l1 = head_b[1];
        #pragma unroll
        for (int w = 0; w < NQ; ++w) {
            float Sw = red[0][1 + w] + red[1][1 + w] + red[2][1 + w] + red[3][1 + w];
            float z = Tt - 2.0f * Sw;
            l0 += z * head_w[w];
            l1 += z * head_w[NQ + w];
        }
        float m = fmaxf(l0, l1);
        float lse = m + __logf(__expf(l0 - m) + __expf(l1 - m));
        out[b * 2 + 0] = l0 - lse;
        out[b * 2 + 1] = l1 - lse;
    }
}

extern "C" void kernel_launch(void* const* d_in, const int* in_sizes, int n_in,
                              void* d_out, int out_size, void* d_ws, size_t ws_size,
                              hipStream_t stream) {
    const float* x      = (const float*)d_in[0];
    const float* params = (const float*)d_in[1];
    const float* head_w = (const float*)d_in[2];
    const float* head_b = (const float*)d_in[3];
    float* out = (float*)d_out;

    const int batch = in_sizes[0] / NQ;   // 512
    qsim_kernel<<<batch, TPB, 0, stream>>>(x, params, head_w, head_b, out);
}

// Round 9
// 13.955 us; speedup vs baseline: 1.7417x; 1.7417x over previous
//
#include <hip/hip_runtime.h>
#include <math.h>

#define NQ 12
#define TPB 256
#define DEPTH 4

typedef float v4f __attribute__((ext_vector_type(4)));
typedef _Float16 v4h __attribute__((ext_vector_type(4)));
typedef unsigned int u32;

// readlane broadcast (literal lane index after unroll)
#define RL(v, l) __uint_as_float(__builtin_amdgcn_readlane(__float_as_uint(v), (l)))

// ---- wave-sum helpers (all-VALU, from R6) ------------------------------
template<int CTRL>
__device__ __forceinline__ float dppf(float v) {
    int r = __builtin_amdgcn_update_dpp(0, __float_as_int(v), CTRL, 0xF, 0xF, true);
    return __int_as_float(r);
}
#if __has_builtin(__builtin_amdgcn_permlane16_swap)
__device__ __forceinline__ void split16(float v, float& v0, float& v1) {
    auto r = __builtin_amdgcn_permlane16_swap(__float_as_uint(v), __float_as_uint(v), false, false);
    v0 = __uint_as_float(r[0]);
    v1 = __uint_as_float(r[1]);
}
#else
__device__ __forceinline__ void split16(float v, float& v0, float& v1) {
    float p = __shfl_xor(v, 16, 64);
    int bit = (__lane_id() >> 4) & 1;
    v0 = bit ? p : v;
    v1 = bit ? v : p;
}
#endif
#if __has_builtin(__builtin_amdgcn_permlane32_swap)
__device__ __forceinline__ void split32(float v, float& v0, float& v1) {
    auto r = __builtin_amdgcn_permlane32_swap(__float_as_uint(v), __float_as_uint(v), false, false);
    v0 = __uint_as_float(r[0]);
    v1 = __uint_as_float(r[1]);
}
#else
__device__ __forceinline__ void split32(float v, float& v0, float& v1) {
    float p = __shfl_xor(v, 32, 64);
    int bit = (__lane_id() >> 5) & 1;
    v0 = bit ? p : v;
    v1 = bit ? v : p;
}
#endif

__device__ __forceinline__ float wave_sum(float y) {
    y += dppf<0xB1>(y);     // xor 1
    y += dppf<0x4E>(y);     // xor 2
    y += dppf<0x124>(y);    // row_ror:4
    y += dppf<0x128>(y);    // row_ror:8
    float a, b;
    split16(y, a, b); y = a + b;
    split32(y, a, b); y = a + b;
    return y;
}

// ---- MFMA plumbing ------------------------------------------------------
__device__ __forceinline__ v4f MFMA16(v4h a, v4h b, v4f c) {
#if __has_builtin(__builtin_amdgcn_mfma_f32_16x16x16f16)
    return __builtin_amdgcn_mfma_f32_16x16x16f16(a, b, c, 0, 0, 0);
#else
    v4f d;
    asm volatile("v_mfma_f32_16x16x16_f16 %0, %1, %2, %3\n\ts_nop 7\n\ts_nop 7"
                 : "=v"(d) : "v"(a), "v"(b), "v"(c));
    return d;
#endif
}

__device__ __forceinline__ v4h pack4(v4f d) {
    auto lo = __builtin_amdgcn_cvt_pkrtz(d[0], d[1]);
    auto hi = __builtin_amdgcn_cvt_pkrtz(d[2], d[3]);
    v4h r;
    r[0] = lo[0]; r[1] = lo[1]; r[2] = hi[0]; r[3] = hi[1];
    return r;
}

// B[k=4h+j][n=i] = G[i][4h+j], G = R(lb3) (x) R(lb2) (x) R(lb1) (x) R(lb0),
// R[new][old] = [[c,-s],[s,c]]. (c3,s3) belong to lb3 (group MSB), etc.
__device__ __forceinline__ v4h buildB(float c3, float s3, float c2, float s2,
                                      float c1, float s1, float c0, float s0,
                                      int i, int h) {
    int i3 = (i >> 3) & 1, i2 = (i >> 2) & 1, i1 = (i >> 1) & 1, i0 = i & 1;
    int k3 = (h >> 1) & 1, k2 = h & 1;
    float f3 = (i3 == k3) ? c3 : (i3 ? s3 : -s3);
    float f2 = (i2 == k2) ? c2 : (i2 ? s2 : -s2);
    float fhi = f3 * f2;
    float e[4];
    #pragma unroll
    for (int j = 0; j < 4; ++j) {
        int k1 = (j >> 1) & 1, k0 = j & 1;
        float f1 = (i1 == k1) ? c1 : (i1 ? s1 : -s1);
        float f0 = (i0 == k0) ? c0 : (i0 ? s0 : -s0);
        e[j] = fhi * f1 * f0;
    }
    auto lo = __builtin_amdgcn_cvt_pkrtz(e[0], e[1]);
    auto hi = __builtin_amdgcn_cvt_pkrtz(e[2], e[3]);
    v4h r;
    r[0] = lo[0]; r[1] = lo[1]; r[2] = hi[0]; r[3] = hi[1];
    return r;
}

// one gate pass: st[r] <- pack(mfma(A=st[r] (==S^T), B=G^T)); layout (R,C)->(C,R')
__device__ __forceinline__ void gate_pass(v4h st[8],
                                          float c3, float s3, float c2, float s2,
                                          float c1, float s1, float c0, float s0,
                                          int i, int h) {
    v4h B = buildB(c3, s3, c2, s2, c1, s1, c0, s0, i, h);
    const v4f z = {0.f, 0.f, 0.f, 0.f};
    #pragma unroll
    for (int r = 0; r < 8; ++r)
        st[r] = pack4(MFMA16(st[r], B, z));
}

__device__ __forceinline__ u32 czpar(int k) {
    return (u32)(__popc(k & (k >> 1)) & 1);
}

__global__ __launch_bounds__(TPB) void qsim_kernel(
    const float* __restrict__ x,        // (512, 12)
    const float* __restrict__ params,   // (48, 12)
    const float* __restrict__ head_w,   // (2, 12)
    const float* __restrict__ head_b,   // (2,)
    float* __restrict__ out)            // (512, 2)
{
    // exchange buffer: [dbuf][comp][c*66 + Rv*4 + (ww|h)] as v4h (Tv innermost)
    __shared__ v4h  xb[2][2][1056];     // 33.8 KB
    __shared__ float red[4][11];

    const int b  = blockIdx.x;
    const int t  = threadIdx.x;
    const int l  = t & 63;
    const int ww = t >> 6;              // wave id (tile-group high bits)
    const int c  = l & 15;              // fragment column
    const int h  = l >> 4;              // fragment row-block

    // one sincos per lane: lanes 0..47 RY angle (d= l/12, w = l%12); 48..59 RX
    float cv, sv;
    {
        int li   = l % 12;
        int idx1 = (l < 48) ? (l * 12 + li) : 0;
        float v1 = params[idx1];
        int i2   = l - 48;
        int idx2 = (i2 >= 0 && i2 < 12) ? (b * 12 + i2) : 0;
        float v2 = x[idx2];
        float th = 0.5f * ((l < 48) ? v1 : ((i2 >= 0 && i2 < 12) ? v2 : 0.0f));
        __sincosf(th, &sv, &cv);
    }
    #define CY(d, w) RL(cv, (d) * 12 + (w))
    #define SY(d, w) RL(sv, (d) * 12 + (w))

    float cx[12], sx[12];
    #pragma unroll
    for (int i = 0; i < 12; ++i) {
        cx[i] = RL(cv, 48 + i);
        sx[i] = RL(sv, 48 + i);
    }

    // ---- init: layout L0 = (rows=g0, cols=g1, tiles=g2) -------------------
    // tile r: Gv = 4*ww + (r>>1), comp = r&1; element j: row = 4h+j, col = c.
    // amp(k) = m(k) * (-i)^popc(k); m = mg0(row)*mg1(c)*mg2(Gv)
    v4h st[8];
    {
        float mg1c = (c & 8 ? sx[4] : cx[4]) * (c & 4 ? sx[5] : cx[5])
                   * (c & 2 ? sx[6] : cx[6]) * (c & 1 ? sx[7] : cx[7]);
        float m0hi = (h & 2 ? sx[8] : cx[8]) * (h & 1 ? sx[9] : cx[9]);
        float m0lo[4], m2lo[4];
        #pragma unroll
        for (int j = 0; j < 4; ++j) {
            m0lo[j] = (j & 2 ? sx[10] : cx[10]) * (j & 1 ? sx[11] : cx[11]);
            m2lo[j] = (j & 2 ? sx[2]  : cx[2])  * (j & 1 ? sx[3]  : cx[3]);
        }
        float m2hi = (ww & 2 ? sx[0] : cx[0]) * (ww & 1 ? sx[1] : cx[1]);
        int pcc = __popc(c), pch = __popc(h), pcw = __popc(ww);
        #pragma unroll
        for (int r = 0; r < 8; ++r) {
            int comp = r & 1, tl = r >> 1;
            float mt = mg1c * m0hi * m2hi * m2lo[tl];
            int pbase = pcc + pch + pcw + __popc(tl);
            float e[4];
            #pragma unroll
            for (int j = 0; j < 4; ++j) {
                float m = mt * m0lo[j];
                int p = (pbase + __popc(j)) & 3;
                float re = (p == 0) ? m : ((p == 2) ? -m : 0.0f);
                float im = (p == 1) ? -m : ((p == 3) ? m : 0.0f);
                e[j] = comp ? im : re;
            }
            auto lo = __builtin_amdgcn_cvt_pkrtz(e[0], e[1]);
            auto hi = __builtin_amdgcn_cvt_pkrtz(e[2], e[3]);
            st[r][0] = lo[0]; st[r][1] = lo[1]; st[r][2] = hi[0]; st[r][3] = hi[1];
        }
    }

    #define GP(d, X) do { const int wb = 4 * (2 - (X)); \
        gate_pass(st, CY(d, wb), SY(d, wb), CY(d, wb + 1), SY(d, wb + 1), \
                  CY(d, wb + 2), SY(d, wb + 2), CY(d, wb + 3), SY(d, wb + 3), c, h); } while (0)

    // Layout algebra: P:(R,C,T)->(C,R,T) gating R; X:(R,C,T)->(T,C,R).
    // d0: (0,1,2) P0 P1 X P2 -> (1,2,0), CZ k=(c<<8)|(row<<4)|Gv
    // d1: (1,2,0) P1 P2 X P0 -> (2,0,1), CZ k=(row<<8)|(Gv<<4)|c
    // d2: (2,0,1) P2 P0 X P1 -> (0,1,2), CZ k=(Gv<<8)|(c<<4)|row
    // d3: (0,1,2) P0 P1 X P2 -> (1,2,0)  (CZ skipped)
    #pragma unroll
    for (int d = 0; d < DEPTH; ++d) {
        const int A0 = (d == 1) ? 1 : (d == 2) ? 2 : 0;
        const int A1 = (d == 1) ? 2 : (d == 2) ? 0 : 1;
        const int A2 = (d == 1) ? 0 : (d == 2) ? 1 : 2;

        if (A0 == 0) GP(d, 0); else if (A0 == 1) GP(d, 1); else GP(d, 2);
        if (A1 == 0) GP(d, 0); else if (A1 == 1) GP(d, 1); else GP(d, 2);

        // X: rows <-> tiles exchange via LDS (b64 both sides)
        {
            #pragma unroll
            for (int comp = 0; comp < 2; ++comp)
                #pragma unroll
                for (int rowj = 0; rowj < 4; ++rowj) {
                    v4h w;
                    w[0] = st[0 + comp][rowj];
                    w[1] = st[2 + comp][rowj];
                    w[2] = st[4 + comp][rowj];
                    w[3] = st[6 + comp][rowj];
                    xb[d & 1][comp][c * 66 + (4 * h + rowj) * 4 + ww] = w;
                }
            __syncthreads();
            #pragma unroll
            for (int r = 0; r < 8; ++r)
                st[r] = xb[d & 1][r & 1][c * 66 + (4 * ww + (r >> 1)) * 4 + h];
        }

        if (A2 == 0) GP(d, 0); else if (A2 == 1) GP(d, 1); else GP(d, 2);

        // CZ: sign flip where popc(k & k>>1) odd (skip last depth)
        if (d < DEPTH - 1) {
            #pragma unroll
            for (int r = 0; r < 8; ++r) {
                int Gv = 4 * ww + (r >> 1);
                u32 pb[4];
                #pragma unroll
                for (int j = 0; j < 4; ++j) {
                    int row = 4 * h + j;
                    int k = (d == 0) ? ((c << 8) | (row << 4) | Gv)
                          : (d == 1) ? ((row << 8) | (Gv << 4) | c)
                                     : ((Gv << 8) | (c << 4) | row);
                    pb[j] = czpar(k);
                }
                u32 mx = (pb[0] << 15) | (pb[1] << 31);
                u32 my = (pb[2] << 15) | (pb[3] << 31);
                uint2 u = __builtin_bit_cast(uint2, st[r]);
                u.x ^= mx;
                u.y ^= my;
                st[r] = __builtin_bit_cast(v4h, u);
            }
        }
    }

    // ---- reduction; final layout (rows=g1, cols=g2, tiles=g0) -------------
    // wires: w0..w3 = c bits 3..0 (masked); w4 = h>>1, w5 = h&1 (masked);
    // w6 = row bit1 (j&2), w7 = row bit0 (j&1); w8 = ww>>1, w9 = ww&1 (block);
    // w10 = tl>>1 (rp&2), w11 = tl&1 (rp&1).
    float T = 0.f, P6 = 0.f, P7 = 0.f, P10 = 0.f, P11 = 0.f;
    #pragma unroll
    for (int rp = 0; rp < 4; ++rp) {
        #pragma unroll
        for (int j = 0; j < 4; ++j) {
            float re = (float)st[2 * rp][j];
            float im = (float)st[2 * rp + 1][j];
            float p = re * re + im * im;
            T += p;
            if (j & 2)  P6  += p;
            if (j & 1)  P7  += p;
            if (rp & 2) P10 += p;
            if (rp & 1) P11 += p;
        }
    }
    float v[11];
    v[0]  = T;
    v[1]  = (c & 8) ? T : 0.f;    // w0
    v[2]  = (c & 4) ? T : 0.f;    // w1
    v[3]  = (c & 2) ? T : 0.f;    // w2
    v[4]  = (c & 1) ? T : 0.f;    // w3
    v[5]  = (h & 2) ? T : 0.f;    // w4
    v[6]  = (h & 1) ? T : 0.f;    // w5
    v[7]  = P6;
    v[8]  = P7;
    v[9]  = P10;
    v[10] = P11;

    #pragma unroll
    for (int i = 0; i < 11; ++i)
        v[i] = wave_sum(v[i]);

    if ((t & 63) == 0) {
        #pragma unroll
        for (int i = 0; i < 11; ++i) red[ww][i] = v[i];
    }
    __syncthreads();

    if (t == 0) {
        float Tt = red[0][0] + red[1][0] + red[2][0] + red[3][0];
        float S[12];
        #pragma unroll
        for (int i = 0; i < 4; ++i)   // w0..w3
            S[i] = red[0][1 + i] + red[1][1 + i] + red[2][1 + i] + red[3][1 + i];
        S[4] = red[0][5] + red[1][5] + red[2][5] + red[3][5];
        S[5] = red[0][6] + red[1][6] + red[2][6] + red[3][6];
        S[6] = red[0][7] + red[1][7] + red[2][7] + red[3][7];
        S[7] = red[0][8] + red[1][8] + red[2][8] + red[3][8];
        S[8] = red[2][0] + red[3][0];                 // ww>>1
        S[9] = red[1][0] + red[3][0];                 // ww&1
        S[10] = red[0][9] + red[1][9] + red[2][9] + red[3][9];
        S[11] = red[0][10] + red[1][10] + red[2][10] + red[3][10];

        float l0 = head_b[0], l1 = head_b[1];
        #pragma unroll
        for (int w = 0; w < NQ; ++w) {
            float z = Tt - 2.0f * S[w];
            l0 += z * head_w[w];
            l1 += z * head_w[NQ + w];
        }
        float m = fmaxf(l0, l1);
        float lse = m + __logf(__expf(l0 - m) + __expf(l1 - m));
        out[b * 2 + 0] = l0 - lse;
        out[b * 2 + 1] = l1 - lse;
    }
}

extern "C" void kernel_launch(void* const* d_in, const int* in_sizes, int n_in,
                              void* d_out, int out_size, void* d_ws, size_t ws_size,
                              hipStream_t stream) {
    const float* x      = (const float*)d_in[0];
    const float* params = (const float*)d_in[1];
    const float* head_w = (const float*)d_in[2];
    const float* head_b = (const float*)d_in[3];
    float* out = (float*)d_out;

    const int batch = in_sizes[0] / NQ;   // 512
    qsim_kernel<<<batch, TPB, 0, stream>>>(x, params, head_w, head_b, out);
}

// Round 10
// 13.378 us; speedup vs baseline: 1.8169x; 1.0432x over previous
//
#include <hip/hip_runtime.h>
#include <math.h>

#define NQ 12
#define TPB 256
#define DEPTH 4

typedef float v4f __attribute__((ext_vector_type(4)));
typedef _Float16 v4h __attribute__((ext_vector_type(4)));
typedef unsigned int u32;

// readlane broadcast (literal lane index after unroll)
#define RL(v, l) __uint_as_float(__builtin_amdgcn_readlane(__float_as_uint(v), (l)))

// ---- wave-sum helpers (all-VALU, from R6) ------------------------------
template<int CTRL>
__device__ __forceinline__ float dppf(float v) {
    int r = __builtin_amdgcn_update_dpp(0, __float_as_int(v), CTRL, 0xF, 0xF, true);
    return __int_as_float(r);
}
#if __has_builtin(__builtin_amdgcn_permlane16_swap)
__device__ __forceinline__ void split16(float v, float& v0, float& v1) {
    auto r = __builtin_amdgcn_permlane16_swap(__float_as_uint(v), __float_as_uint(v), false, false);
    v0 = __uint_as_float(r[0]);
    v1 = __uint_as_float(r[1]);
}
#else
__device__ __forceinline__ void split16(float v, float& v0, float& v1) {
    float p = __shfl_xor(v, 16, 64);
    int bit = (__lane_id() >> 4) & 1;
    v0 = bit ? p : v;
    v1 = bit ? v : p;
}
#endif
#if __has_builtin(__builtin_amdgcn_permlane32_swap)
__device__ __forceinline__ void split32(float v, float& v0, float& v1) {
    auto r = __builtin_amdgcn_permlane32_swap(__float_as_uint(v), __float_as_uint(v), false, false);
    v0 = __uint_as_float(r[0]);
    v1 = __uint_as_float(r[1]);
}
#else
__device__ __forceinline__ void split32(float v, float& v0, float& v1) {
    float p = __shfl_xor(v, 32, 64);
    int bit = (__lane_id() >> 5) & 1;
    v0 = bit ? p : v;
    v1 = bit ? v : p;
}
#endif

__device__ __forceinline__ float wave_sum(float y) {
    y += dppf<0xB1>(y);     // xor 1
    y += dppf<0x4E>(y);     // xor 2
    y += dppf<0x124>(y);    // row_ror:4
    y += dppf<0x128>(y);    // row_ror:8
    float a, b;
    split16(y, a, b); y = a + b;
    split32(y, a, b); y = a + b;
    return y;
}

// ---- MFMA plumbing ------------------------------------------------------
__device__ __forceinline__ v4f MFMA16(v4h a, v4h b, v4f c) {
#if __has_builtin(__builtin_amdgcn_mfma_f32_16x16x16f16)
    return __builtin_amdgcn_mfma_f32_16x16x16f16(a, b, c, 0, 0, 0);
#else
    v4f d;
    asm volatile("v_mfma_f32_16x16x16_f16 %0, %1, %2, %3\n\ts_nop 7\n\ts_nop 7"
                 : "=v"(d) : "v"(a), "v"(b), "v"(c));
    return d;
#endif
}

__device__ __forceinline__ v4h pack4(v4f d) {
    auto lo = __builtin_amdgcn_cvt_pkrtz(d[0], d[1]);
    auto hi = __builtin_amdgcn_cvt_pkrtz(d[2], d[3]);
    v4h r;
    r[0] = lo[0]; r[1] = lo[1]; r[2] = hi[0]; r[3] = hi[1];
    return r;
}

// B[k=4h+j][n=i] = G[i][4h+j], G = R(lb3) (x) R(lb2) (x) R(lb1) (x) R(lb0),
// R[new][old] = [[c,-s],[s,c]]. f(i,k) = (i==k)? c : (i? s : -s).
__device__ __forceinline__ v4h buildB(float c3, float s3, float c2, float s2,
                                      float c1, float s1, float c0, float s0,
                                      int i, int h) {
    const bool i3 = (i >> 3) & 1, i2 = (i >> 2) & 1, i1 = (i >> 1) & 1, i0 = i & 1;
    const bool k3 = (h >> 1) & 1, k2 = h & 1;
    float t3  = i3 ? s3 : -s3;
    float f3  = (i3 == k3) ? c3 : t3;
    float t2  = i2 ? s2 : -s2;
    float f2  = (i2 == k2) ? c2 : t2;
    float fhi = f3 * f2;
    float f0a = i0 ? s0 : c0;     // k0 = 0
    float f0b = i0 ? c0 : -s0;    // k0 = 1
    float f1a = i1 ? s1 : c1;     // k1 = 0
    float f1b = i1 ? c1 : -s1;    // k1 = 1
    float e0 = fhi * (f1a * f0a);
    float e1 = fhi * (f1a * f0b);
    float e2 = fhi * (f1b * f0a);
    float e3 = fhi * (f1b * f0b);
    auto lo = __builtin_amdgcn_cvt_pkrtz(e0, e1);
    auto hi = __builtin_amdgcn_cvt_pkrtz(e2, e3);
    v4h r;
    r[0] = lo[0]; r[1] = lo[1]; r[2] = hi[0]; r[3] = hi[1];
    return r;
}

// one gate pass: st[r] <- pack(mfma(A=st[r] (==S^T), B=G^T)); layout (R,C)->(C,R')
__device__ __forceinline__ void gate_pass(v4h st[8],
                                          float c3, float s3, float c2, float s2,
                                          float c1, float s1, float c0, float s0,
                                          int i, int h) {
    v4h B = buildB(c3, s3, c2, s2, c1, s1, c0, s0, i, h);
    const v4f z = {0.f, 0.f, 0.f, 0.f};
    #pragma unroll
    for (int r = 0; r < 8; ++r)
        st[r] = pack4(MFMA16(st[r], B, z));
}

__global__ __launch_bounds__(TPB) void qsim_kernel(
    const float* __restrict__ x,        // (512, 12)
    const float* __restrict__ params,   // (48, 12)
    const float* __restrict__ head_w,   // (2, 12)
    const float* __restrict__ head_b,   // (2,)
    float* __restrict__ out)            // (512, 2)
{
    // exchange buffer: [dbuf][comp][c*66 + Rv*4 + (ww|h)] as v4h (Tv innermost)
    __shared__ v4h  xb[2][2][1056];     // 33.8 KB
    __shared__ float red[4][11];

    const int b  = blockIdx.x;
    const int t  = threadIdx.x;
    const int l  = t & 63;
    const int ww = t >> 6;              // wave id (tile-group high bits)
    const int c  = l & 15;              // fragment column
    const int h  = l >> 4;              // fragment row-block

    // one sincos per lane: lanes 0..47 RY angle (d= l/12, w = l%12); 48..59 RX
    float cv, sv;
    {
        int li   = l % 12;
        int idx1 = (l < 48) ? (l * 12 + li) : 0;
        float v1 = params[idx1];
        int i2   = l - 48;
        int idx2 = (i2 >= 0 && i2 < 12) ? (b * 12 + i2) : 0;
        float v2 = x[idx2];
        float th = 0.5f * ((l < 48) ? v1 : ((i2 >= 0 && i2 < 12) ? v2 : 0.0f));
        __sincosf(th, &sv, &cv);
    }
    #define CY(d, w) RL(cv, (d) * 12 + (w))
    #define SY(d, w) RL(sv, (d) * 12 + (w))

    float cx[12], sx[12];
    #pragma unroll
    for (int i = 0; i < 12; ++i) {
        cx[i] = RL(cv, 48 + i);
        sx[i] = RL(sv, 48 + i);
    }

    // ---- init: layout L0 = (rows=g0, cols=g1, tiles=g2) -------------------
    // tile r: Gv = 4*ww + (r>>1), comp = r&1; element j: row = 4h+j, col = c.
    // amp(k) = m(k) * (-i)^popc(k); m = mg0(row)*mg1(c)*mg2(Gv).
    // m shared across comp; phase p selects which comp gets +-m.
    v4h st[8];
    {
        float mg1c = (c & 8 ? sx[4] : cx[4]) * (c & 4 ? sx[5] : cx[5])
                   * (c & 2 ? sx[6] : cx[6]) * (c & 1 ? sx[7] : cx[7]);
        float m0hi = (h & 2 ? sx[8] : cx[8]) * (h & 1 ? sx[9] : cx[9]);
        float m0lo[4], m2lo[4];
        #pragma unroll
        for (int j = 0; j < 4; ++j) {
            m0lo[j] = (j & 2 ? sx[10] : cx[10]) * (j & 1 ? sx[11] : cx[11]);
            m2lo[j] = (j & 2 ? sx[2]  : cx[2])  * (j & 1 ? sx[3]  : cx[3]);
        }
        float m2hi = (ww & 2 ? sx[0] : cx[0]) * (ww & 1 ? sx[1] : cx[1]);
        const int pbase0 = __popc(c) + __popc(h) + __popc(ww);
        const float mhi3 = mg1c * m0hi * m2hi;
        #pragma unroll
        for (int tl = 0; tl < 4; ++tl) {
            float mt = mhi3 * m2lo[tl];
            int pb = pbase0 + __popc(tl);
            float er[4], ei[4];
            #pragma unroll
            for (int j = 0; j < 4; ++j) {
                float m = mt * m0lo[j];
                int p = (pb + __popc(j)) & 3;
                // re = +m (p=0), -m (p=2), 0 (odd); im = -m (p=1), +m (p=3), 0 (even)
                float sm = __uint_as_float(__float_as_uint(m) ^ ((u32)(p >> 1) << 31));
                bool odd = p & 1;
                er[j] = odd ? 0.0f : sm;
                ei[j] = odd ? __uint_as_float(__float_as_uint(sm) ^ 0x80000000u) : 0.0f;
            }
            {
                auto lo = __builtin_amdgcn_cvt_pkrtz(er[0], er[1]);
                auto hi = __builtin_amdgcn_cvt_pkrtz(er[2], er[3]);
                st[2*tl][0] = lo[0]; st[2*tl][1] = lo[1];
                st[2*tl][2] = hi[0]; st[2*tl][3] = hi[1];
            }
            {
                auto lo = __builtin_amdgcn_cvt_pkrtz(ei[0], ei[1]);
                auto hi = __builtin_amdgcn_cvt_pkrtz(ei[2], ei[3]);
                st[2*tl+1][0] = lo[0]; st[2*tl+1][1] = lo[1];
                st[2*tl+1][2] = hi[0]; st[2*tl+1][3] = hi[1];
            }
        }
    }

    // ---- CZ parity precompute ---------------------------------------------
    // parity(k) over 12-bit k = (A<<8)|(B<<4)|C factors as
    // par_in(A)^par_in(B)^par_in(C)^(A0&B3)^(B0&C3).
    // Layouts: d0 k=(c,row,Gv); d1 k=(row,Gv,c); d2 k=(Gv,c,row).
    // parity(d,tl,j) = A_d[j] ^ B_d[tl]; A packs into per-depth sign words,
    // B packs into the 12-bit register BB (bit 4*d+tl).
    u32 MX01, MY01, MX2, MY2, BB;
    {
        const u32 c0b = c & 1, c3b = (c >> 3) & 1;
        const u32 h0b = h & 1, h1b = (h >> 1) & 1;
        const u32 w0b = ww & 1, w1b = (ww >> 1) & 1;
        const u32 pc  = (u32)(__popc(c & (c >> 1)) & 1);
        const u32 Xb  = c0b & h1b;                 // c0 & row3
        const u32 hh  = h0b & h1b;
        const u32 pr_[4] = { hh, hh, h0b ^ hh, 1u ^ h0b ^ hh };   // par_in(4h+j)
        const u32 wwp = w0b & w1b;
        const u32 pg_[4] = { wwp, wwp, w0b ^ wwp, 1u ^ w0b ^ wwp }; // par_in(4ww+tl)
        // d0/d1 share A_j = pr[j] ^ (j odd ? ww1 : 0)  (the row0&Gv3 term); d2: A_j = pr[j]
        MX01 = (pr_[0] << 15) | ((pr_[1] ^ w1b) << 31);
        MY01 = (pr_[2] << 15) | ((pr_[3] ^ w1b) << 31);
        MX2  = (pr_[0] << 15) | (pr_[1] << 31);
        MY2  = (pr_[2] << 15) | (pr_[3] << 31);
        const u32 pcX = pc ^ Xb;
        BB = 0;
        #pragma unroll
        for (int tl = 0; tl < 4; ++tl) {
            u32 z  = (tl & 1) ? c3b : 0u;          // Gv0 & c3 term
            u32 B0 = pg_[tl] ^ pcX;                // d0: pc ^ X
            u32 B1 = pg_[tl] ^ z ^ pc;             // d1: pc ^ Z
            u32 B2 = pg_[tl] ^ z ^ pcX;            // d2: pc ^ X ^ Z
            BB |= (B0 << (0 + tl)) | (B1 << (4 + tl)) | (B2 << (8 + tl));
        }
    }

    #define GP(d, X) do { const int wb = 4 * (2 - (X)); \
        gate_pass(st, CY(d, wb), SY(d, wb), CY(d, wb + 1), SY(d, wb + 1), \
                  CY(d, wb + 2), SY(d, wb + 2), CY(d, wb + 3), SY(d, wb + 3), c, h); } while (0)

    // Layout algebra: P:(R,C,T)->(C,R,T) gating R; X:(R,C,T)->(T,C,R).
    // d0: (0,1,2) P0 P1 X P2 -> (1,2,0); d1: P1 P2 X P0 -> (2,0,1);
    // d2: P2 P0 X P1 -> (0,1,2); d3: P0 P1 X P2 (CZ skipped).
    #pragma unroll
    for (int d = 0; d < DEPTH; ++d) {
        const int A0 = (d == 1) ? 1 : (d == 2) ? 2 : 0;
        const int A1 = (d == 1) ? 2 : (d == 2) ? 0 : 1;
        const int A2 = (d == 1) ? 0 : (d == 2) ? 1 : 2;

        if (A0 == 0) GP(d, 0); else if (A0 == 1) GP(d, 1); else GP(d, 2);
        if (A1 == 0) GP(d, 0); else if (A1 == 1) GP(d, 1); else GP(d, 2);

        // X: rows <-> tiles exchange via LDS (b64 both sides)
        {
            #pragma unroll
            for (int comp = 0; comp < 2; ++comp)
                #pragma unroll
                for (int rowj = 0; rowj < 4; ++rowj) {
                    v4h w;
                    w[0] = st[0 + comp][rowj];
                    w[1] = st[2 + comp][rowj];
                    w[2] = st[4 + comp][rowj];
                    w[3] = st[6 + comp][rowj];
                    xb[d & 1][comp][c * 66 + (4 * h + rowj) * 4 + ww] = w;
                }
            __syncthreads();
            #pragma unroll
            for (int r = 0; r < 8; ++r)
                st[r] = xb[d & 1][r & 1][c * 66 + (4 * ww + (r >> 1)) * 4 + h];
        }

        if (A2 == 0) GP(d, 0); else if (A2 == 1) GP(d, 1); else GP(d, 2);

        // CZ sign flips (skip last depth: |amp|^2 unaffected)
        if (d < DEPTH - 1) {
            const u32 MXd = (d == 2) ? MX2 : MX01;
            const u32 MYd = (d == 2) ? MY2 : MY01;
            #pragma unroll
            for (int tl = 0; tl < 4; ++tl) {
                u32 Bbit = (BB >> (4 * d + tl)) & 1u;
                u32 fm = (0u - Bbit) & 0x80008000u;
                u32 mx = MXd ^ fm, my = MYd ^ fm;
                #pragma unroll
                for (int comp = 0; comp < 2; ++comp) {
                    uint2 u = __builtin_bit_cast(uint2, st[2 * tl + comp]);
                    u.x ^= mx;
                    u.y ^= my;
                    st[2 * tl + comp] = __builtin_bit_cast(v4h, u);
                }
            }
        }
    }

    // ---- reduction; final layout (rows=g1, cols=g2, tiles=g0) -------------
    float T = 0.f, P6 = 0.f, P7 = 0.f, P10 = 0.f, P11 = 0.f;
    #pragma unroll
    for (int rp = 0; rp < 4; ++rp) {
        #pragma unroll
        for (int j = 0; j < 4; ++j) {
            float re = (float)st[2 * rp][j];
            float im = (float)st[2 * rp + 1][j];
            float p = re * re + im * im;
            T += p;
            if (j & 2)  P6  += p;
            if (j & 1)  P7  += p;
            if (rp & 2) P10 += p;
            if (rp & 1) P11 += p;
        }
    }
    float v[11];
    v[0]  = T;
    v[1]  = (c & 8) ? T : 0.f;    // w0
    v[2]  = (c & 4) ? T : 0.f;    // w1
    v[3]  = (c & 2) ? T : 0.f;    // w2
    v[4]  = (c & 1) ? T : 0.f;    // w3
    v[5]  = (h & 2) ? T : 0.f;    // w4
    v[6]  = (h & 1) ? T : 0.f;    // w5
    v[7]  = P6;
    v[8]  = P7;
    v[9]  = P10;
    v[10] = P11;

    #pragma unroll
    for (int i = 0; i < 11; ++i)
        v[i] = wave_sum(v[i]);

    if ((t & 63) == 0) {
        #pragma unroll
        for (int i = 0; i < 11; ++i) red[ww][i] = v[i];
    }
    __syncthreads();

    if (t == 0) {
        float Tt = red[0][0] + red[1][0] + red[2][0] + red[3][0];
        float S[12];
        #pragma unroll
        for (int i = 0; i < 4; ++i)   // w0..w3
            S[i] = red[0][1 + i] + red[1][1 + i] + red[2][1 + i] + red[3][1 + i];
        S[4] = red[0][5] + red[1][5] + red[2][5] + red[3][5];
        S[5] = red[0][6] + red[1][6] + red[2][6] + red[3][6];
        S[6] = red[0][7] + red[1][7] + red[2][7] + red[3][7];
        S[7] = red[0][8] + red[1][8] + red[2][8] + red[3][8];
        S[8] = red[2][0] + red[3][0];                 // ww>>1
        S[9] = red[1][0] + red[3][0];                 // ww&1
        S[10] = red[0][9] + red[1][9] + red[2][9] + red[3][9];
        S[11] = red[0][10] + red[1][10] + red[2][10] + red[3][10];

        float l0 = head_b[0], l1 = head_b[1];
        #pragma unroll
        for (int w = 0; w < NQ; ++w) {
            float z = Tt - 2.0f * S[w];
            l0 += z * head_w[w];
            l1 += z * head_w[NQ + w];
        }
        float m = fmaxf(l0, l1);
        float lse = m + __logf(__expf(l0 - m) + __expf(l1 - m));
        out[b * 2 + 0] = l0 - lse;
        out[b * 2 + 1] = l1 - lse;
    }
}

extern "C" void kernel_launch(void* const* d_in, const int* in_sizes, int n_in,
                              void* d_out, int out_size, void* d_ws, size_t ws_size,
                              hipStream_t stream) {
    const float* x      = (const float*)d_in[0];
    const float* params = (const float*)d_in[1];
    const float* head_w = (const float*)d_in[2];
    const float* head_b = (const float*)d_in[3];
    float* out = (float*)d_out;

    const int batch = in_sizes[0] / NQ;   // 512
    qsim_kernel<<<batch, TPB, 0, stream>>>(x, params, head_w, head_b, out);
}

// Round 11
// 13.338 us; speedup vs baseline: 1.8223x; 1.0030x over previous
//
#include <hip/hip_runtime.h>
#include <math.h>

#define NQ 12
#define TPB 256
#define DEPTH 4

typedef float v4f __attribute__((ext_vector_type(4)));
typedef _Float16 v4h __attribute__((ext_vector_type(4)));
typedef unsigned int u32;

// readlane broadcast (literal lane index after unroll)
#define RL(v, l) __uint_as_float(__builtin_amdgcn_readlane(__float_as_uint(v), (l)))

// ---- wave-sum helpers (all-VALU, from R6) ------------------------------
template<int CTRL>
__device__ __forceinline__ float dppf(float v) {
    int r = __builtin_amdgcn_update_dpp(0, __float_as_int(v), CTRL, 0xF, 0xF, true);
    return __int_as_float(r);
}
#if __has_builtin(__builtin_amdgcn_permlane16_swap)
__device__ __forceinline__ void split16(float v, float& v0, float& v1) {
    auto r = __builtin_amdgcn_permlane16_swap(__float_as_uint(v), __float_as_uint(v), false, false);
    v0 = __uint_as_float(r[0]);
    v1 = __uint_as_float(r[1]);
}
#else
__device__ __forceinline__ void split16(float v, float& v0, float& v1) {
    float p = __shfl_xor(v, 16, 64);
    int bit = (__lane_id() >> 4) & 1;
    v0 = bit ? p : v;
    v1 = bit ? v : p;
}
#endif
#if __has_builtin(__builtin_amdgcn_permlane32_swap)
__device__ __forceinline__ void split32(float v, float& v0, float& v1) {
    auto r = __builtin_amdgcn_permlane32_swap(__float_as_uint(v), __float_as_uint(v), false, false);
    v0 = __uint_as_float(r[0]);
    v1 = __uint_as_float(r[1]);
}
#else
__device__ __forceinline__ void split32(float v, float& v0, float& v1) {
    float p = __shfl_xor(v, 32, 64);
    int bit = (__lane_id() >> 5) & 1;
    v0 = bit ? p : v;
    v1 = bit ? v : p;
}
#endif

__device__ __forceinline__ float wave_sum(float y) {
    y += dppf<0xB1>(y);     // xor 1
    y += dppf<0x4E>(y);     // xor 2
    y += dppf<0x124>(y);    // row_ror:4
    y += dppf<0x128>(y);    // row_ror:8
    float a, b;
    split16(y, a, b); y = a + b;
    split32(y, a, b); y = a + b;
    return y;
}

// ---- MFMA plumbing ------------------------------------------------------
__device__ __forceinline__ v4f MFMA16(v4h a, v4h b, v4f c) {
#if __has_builtin(__builtin_amdgcn_mfma_f32_16x16x16f16)
    return __builtin_amdgcn_mfma_f32_16x16x16f16(a, b, c, 0, 0, 0);
#else
    v4f d;
    asm volatile("v_mfma_f32_16x16x16_f16 %0, %1, %2, %3\n\ts_nop 7\n\ts_nop 7"
                 : "=v"(d) : "v"(a), "v"(b), "v"(c));
    return d;
#endif
}

__device__ __forceinline__ v4h pack4(v4f d) {
    auto lo = __builtin_amdgcn_cvt_pkrtz(d[0], d[1]);
    auto hi = __builtin_amdgcn_cvt_pkrtz(d[2], d[3]);
    v4h r;
    r[0] = lo[0]; r[1] = lo[1]; r[2] = hi[0]; r[3] = hi[1];
    return r;
}

// B[k=4h+j][n=i] = G[i][4h+j], G = R(lb3) (x) R(lb2) (x) R(lb1) (x) R(lb0),
// R[new][old] = [[c,-s],[s,c]]. f(i,k) = (i==k)? c : (i? s : -s).
__device__ __forceinline__ v4h buildB(float c3, float s3, float c2, float s2,
                                      float c1, float s1, float c0, float s0,
                                      int i, int h) {
    const bool i3 = (i >> 3) & 1, i2 = (i >> 2) & 1, i1 = (i >> 1) & 1, i0 = i & 1;
    const bool k3 = (h >> 1) & 1, k2 = h & 1;
    float t3  = i3 ? s3 : -s3;
    float f3  = (i3 == k3) ? c3 : t3;
    float t2  = i2 ? s2 : -s2;
    float f2  = (i2 == k2) ? c2 : t2;
    float fhi = f3 * f2;
    float f0a = i0 ? s0 : c0;     // k0 = 0
    float f0b = i0 ? c0 : -s0;    // k0 = 1
    float f1a = i1 ? s1 : c1;     // k1 = 0
    float f1b = i1 ? c1 : -s1;    // k1 = 1
    float e0 = fhi * (f1a * f0a);
    float e1 = fhi * (f1a * f0b);
    float e2 = fhi * (f1b * f0a);
    float e3 = fhi * (f1b * f0b);
    auto lo = __builtin_amdgcn_cvt_pkrtz(e0, e1);
    auto hi = __builtin_amdgcn_cvt_pkrtz(e2, e3);
    v4h r;
    r[0] = lo[0]; r[1] = lo[1]; r[2] = hi[0]; r[3] = hi[1];
    return r;
}

// one gate pass: st[r] <- pack(mfma(A=st[r] (==S^T), B=G^T)); layout (R,C)->(C,R')
__device__ __forceinline__ void gate_pass(v4h st[8],
                                          float c3, float s3, float c2, float s2,
                                          float c1, float s1, float c0, float s0,
                                          int i, int h) {
    v4h B = buildB(c3, s3, c2, s2, c1, s1, c0, s0, i, h);
    const v4f z = {0.f, 0.f, 0.f, 0.f};
    #pragma unroll
    for (int r = 0; r < 8; ++r)
        st[r] = pack4(MFMA16(st[r], B, z));
}

__global__ __launch_bounds__(TPB) void qsim_kernel(
    const float* __restrict__ x,        // (512, 12)
    const float* __restrict__ params,   // (48, 12)
    const float* __restrict__ head_w,   // (2, 12)
    const float* __restrict__ head_b,   // (2,)
    float* __restrict__ out)            // (512, 2)
{
    // exchange: [dbuf][comp][Rv][Gvh][c(+pad to 17)] as v4h (Gvl in vector).
    // c innermost -> write addr%16 = 4*rowj + ww + c (2-way per half-wave);
    // read addr%16 = 4*tl + h + c (2-way per half-wave). Conflict-minimal b64.
    __shared__ v4h  xb[2][2][16][4][17];   // 34 KB
    __shared__ float red[4][11];

    const int b  = blockIdx.x;
    const int t  = threadIdx.x;
    const int l  = t & 63;
    const int ww = t >> 6;              // wave id (tile-group high bits)
    const int c  = l & 15;              // fragment column
    const int h  = l >> 4;              // fragment row-block

    // one sincos per lane: lanes 0..47 RY angle (d= l/12, w = l%12); 48..59 RX
    float cv, sv;
    {
        int li   = l % 12;
        int idx1 = (l < 48) ? (l * 12 + li) : 0;
        float v1 = params[idx1];
        int i2   = l - 48;
        int idx2 = (i2 >= 0 && i2 < 12) ? (b * 12 + i2) : 0;
        float v2 = x[idx2];
        float th = 0.5f * ((l < 48) ? v1 : ((i2 >= 0 && i2 < 12) ? v2 : 0.0f));
        __sincosf(th, &sv, &cv);
    }
    #define CY(d, w) RL(cv, (d) * 12 + (w))
    #define SY(d, w) RL(sv, (d) * 12 + (w))

    float cx[12], sx[12];
    #pragma unroll
    for (int i = 0; i < 12; ++i) {
        cx[i] = RL(cv, 48 + i);
        sx[i] = RL(sv, 48 + i);
    }

    // ---- init: layout L0 = (rows=g0, cols=g1, tiles=g2) -------------------
    v4h st[8];
    {
        float mg1c = (c & 8 ? sx[4] : cx[4]) * (c & 4 ? sx[5] : cx[5])
                   * (c & 2 ? sx[6] : cx[6]) * (c & 1 ? sx[7] : cx[7]);
        float m0hi = (h & 2 ? sx[8] : cx[8]) * (h & 1 ? sx[9] : cx[9]);
        float m0lo[4], m2lo[4];
        #pragma unroll
        for (int j = 0; j < 4; ++j) {
            m0lo[j] = (j & 2 ? sx[10] : cx[10]) * (j & 1 ? sx[11] : cx[11]);
            m2lo[j] = (j & 2 ? sx[2]  : cx[2])  * (j & 1 ? sx[3]  : cx[3]);
        }
        float m2hi = (ww & 2 ? sx[0] : cx[0]) * (ww & 1 ? sx[1] : cx[1]);
        const int pbase0 = __popc(c) + __popc(h) + __popc(ww);
        const float mhi3 = mg1c * m0hi * m2hi;
        #pragma unroll
        for (int tl = 0; tl < 4; ++tl) {
            float mt = mhi3 * m2lo[tl];
            int pb = pbase0 + __popc(tl);
            float er[4], ei[4];
            #pragma unroll
            for (int j = 0; j < 4; ++j) {
                float m = mt * m0lo[j];
                int p = (pb + __popc(j)) & 3;
                float sm = __uint_as_float(__float_as_uint(m) ^ ((u32)(p >> 1) << 31));
                bool odd = p & 1;
                er[j] = odd ? 0.0f : sm;
                ei[j] = odd ? __uint_as_float(__float_as_uint(sm) ^ 0x80000000u) : 0.0f;
            }
            {
                auto lo = __builtin_amdgcn_cvt_pkrtz(er[0], er[1]);
                auto hi = __builtin_amdgcn_cvt_pkrtz(er[2], er[3]);
                st[2*tl][0] = lo[0]; st[2*tl][1] = lo[1];
                st[2*tl][2] = hi[0]; st[2*tl][3] = hi[1];
            }
            {
                auto lo = __builtin_amdgcn_cvt_pkrtz(ei[0], ei[1]);
                auto hi = __builtin_amdgcn_cvt_pkrtz(ei[2], ei[3]);
                st[2*tl+1][0] = lo[0]; st[2*tl+1][1] = lo[1];
                st[2*tl+1][2] = hi[0]; st[2*tl+1][3] = hi[1];
            }
        }
    }

    // ---- CZ parity precompute (R10 decomposition) --------------------------
    u32 MX01, MY01, MX2, MY2, BB;
    {
        const u32 c0b = c & 1, c3b = (c >> 3) & 1;
        const u32 h0b = h & 1, h1b = (h >> 1) & 1;
        const u32 w0b = ww & 1, w1b = (ww >> 1) & 1;
        const u32 pc  = (u32)(__popc(c & (c >> 1)) & 1);
        const u32 Xb  = c0b & h1b;                 // c0 & row3
        const u32 hh  = h0b & h1b;
        const u32 pr_[4] = { hh, hh, h0b ^ hh, 1u ^ h0b ^ hh };   // par_in(4h+j)
        const u32 wwp = w0b & w1b;
        const u32 pg_[4] = { wwp, wwp, w0b ^ wwp, 1u ^ w0b ^ wwp }; // par_in(4ww+tl)
        MX01 = (pr_[0] << 15) | ((pr_[1] ^ w1b) << 31);
        MY01 = (pr_[2] << 15) | ((pr_[3] ^ w1b) << 31);
        MX2  = (pr_[0] << 15) | (pr_[1] << 31);
        MY2  = (pr_[2] << 15) | (pr_[3] << 31);
        const u32 pcX = pc ^ Xb;
        BB = 0;
        #pragma unroll
        for (int tl = 0; tl < 4; ++tl) {
            u32 z  = (tl & 1) ? c3b : 0u;          // Gv0 & c3 term
            u32 B0 = pg_[tl] ^ pcX;
            u32 B1 = pg_[tl] ^ z ^ pc;
            u32 B2 = pg_[tl] ^ z ^ pcX;
            BB |= (B0 << (0 + tl)) | (B1 << (4 + tl)) | (B2 << (8 + tl));
        }
    }

    #define GP(d, X) do { const int wb = 4 * (2 - (X)); \
        gate_pass(st, CY(d, wb), SY(d, wb), CY(d, wb + 1), SY(d, wb + 1), \
                  CY(d, wb + 2), SY(d, wb + 2), CY(d, wb + 3), SY(d, wb + 3), c, h); } while (0)

    // d0: (0,1,2) P0 P1 X P2 -> (1,2,0); d1: P1 P2 X P0 -> (2,0,1);
    // d2: P2 P0 X P1 -> (0,1,2); d3: P0 P1 X P2 (CZ skipped).
    #pragma unroll
    for (int d = 0; d < DEPTH; ++d) {
        const int A0 = (d == 1) ? 1 : (d == 2) ? 2 : 0;
        const int A1 = (d == 1) ? 2 : (d == 2) ? 0 : 1;
        const int A2 = (d == 1) ? 0 : (d == 2) ? 1 : 2;

        if (A0 == 0) GP(d, 0); else if (A0 == 1) GP(d, 1); else GP(d, 2);
        if (A1 == 0) GP(d, 0); else if (A1 == 1) GP(d, 1); else GP(d, 2);

        // X: rows <-> tiles exchange via LDS (conflict-minimal layout)
        {
            #pragma unroll
            for (int comp = 0; comp < 2; ++comp)
                #pragma unroll
                for (int rowj = 0; rowj < 4; ++rowj) {
                    v4h w;
                    w[0] = st[0 + comp][rowj];
                    w[1] = st[2 + comp][rowj];
                    w[2] = st[4 + comp][rowj];
                    w[3] = st[6 + comp][rowj];
                    xb[d & 1][comp][4 * h + rowj][ww][c] = w;
                }
            __syncthreads();
            #pragma unroll
            for (int r = 0; r < 8; ++r)
                st[r] = xb[d & 1][r & 1][4 * ww + (r >> 1)][h][c];
        }

        if (A2 == 0) GP(d, 0); else if (A2 == 1) GP(d, 1); else GP(d, 2);

        // CZ sign flips (skip last depth: |amp|^2 unaffected)
        if (d < DEPTH - 1) {
            const u32 MXd = (d == 2) ? MX2 : MX01;
            const u32 MYd = (d == 2) ? MY2 : MY01;
            #pragma unroll
            for (int tl = 0; tl < 4; ++tl) {
                u32 Bbit = (BB >> (4 * d + tl)) & 1u;
                u32 fm = (0u - Bbit) & 0x80008000u;
                u32 mx = MXd ^ fm, my = MYd ^ fm;
                #pragma unroll
                for (int comp = 0; comp < 2; ++comp) {
                    uint2 u = __builtin_bit_cast(uint2, st[2 * tl + comp]);
                    u.x ^= mx;
                    u.y ^= my;
                    st[2 * tl + comp] = __builtin_bit_cast(v4h, u);
                }
            }
        }
    }

    // ---- reduction; final layout (rows=g1, cols=g2, tiles=g0) -------------
    float T = 0.f, P6 = 0.f, P7 = 0.f, P10 = 0.f, P11 = 0.f;
    #pragma unroll
    for (int rp = 0; rp < 4; ++rp) {
        #pragma unroll
        for (int j = 0; j < 4; ++j) {
            float re = (float)st[2 * rp][j];
            float im = (float)st[2 * rp + 1][j];
            float p = re * re + im * im;
            T += p;
            if (j & 2)  P6  += p;
            if (j & 1)  P7  += p;
            if (rp & 2) P10 += p;
            if (rp & 1) P11 += p;
        }
    }
    float v[11];
    v[0]  = T;
    v[1]  = (c & 8) ? T : 0.f;    // w0
    v[2]  = (c & 4) ? T : 0.f;    // w1
    v[3]  = (c & 2) ? T : 0.f;    // w2
    v[4]  = (c & 1) ? T : 0.f;    // w3
    v[5]  = (h & 2) ? T : 0.f;    // w4
    v[6]  = (h & 1) ? T : 0.f;    // w5
    v[7]  = P6;
    v[8]  = P7;
    v[9]  = P10;
    v[10] = P11;

    #pragma unroll
    for (int i = 0; i < 11; ++i)
        v[i] = wave_sum(v[i]);

    if ((t & 63) == 0) {
        #pragma unroll
        for (int i = 0; i < 11; ++i) red[ww][i] = v[i];
    }
    __syncthreads();

    if (t == 0) {
        float Tt = red[0][0] + red[1][0] + red[2][0] + red[3][0];
        float S[12];
        #pragma unroll
        for (int i = 0; i < 4; ++i)   // w0..w3
            S[i] = red[0][1 + i] + red[1][1 + i] + red[2][1 + i] + red[3][1 + i];
        S[4] = red[0][5] + red[1][5] + red[2][5] + red[3][5];
        S[5] = red[0][6] + red[1][6] + red[2][6] + red[3][6];
        S[6] = red[0][7] + red[1][7] + red[2][7] + red[3][7];
        S[7] = red[0][8] + red[1][8] + red[2][8] + red[3][8];
        S[8] = red[2][0] + red[3][0];                 // ww>>1
        S[9] = red[1][0] + red[3][0];                 // ww&1
        S[10] = red[0][9] + red[1][9] + red[2][9] + red[3][9];
        S[11] = red[0][10] + red[1][10] + red[2][10] + red[3][10];

        float l0 = head_b[0], l1 = head_b[1];
        #pragma unroll
        for (int w = 0; w < NQ; ++w) {
            float z = Tt - 2.0f * S[w];
            l0 += z * head_w[w];
            l1 += z * head_w[NQ + w];
        }
        float m = fmaxf(l0, l1);
        float lse = m + __logf(__expf(l0 - m) + __expf(l1 - m));
        out[b * 2 + 0] = l0 - lse;
        out[b * 2 + 1] = l1 - lse;
    }
}

extern "C" void kernel_launch(void* const* d_in, const int* in_sizes, int n_in,
                              void* d_out, int out_size, void* d_ws, size_t ws_size,
                              hipStream_t stream) {
    const float* x      = (const float*)d_in[0];
    const float* params = (const float*)d_in[1];
    const float* head_w = (const float*)d_in[2];
    const float* head_b = (const float*)d_in[3];
    float* out = (float*)d_out;

    const int batch = in_sizes[0] / NQ;   // 512
    qsim_kernel<<<batch, TPB, 0, stream>>>(x, params, head_w, head_b, out);
}